// Round 1
// baseline (495.045 us; speedup 1.0000x reference)
//
#include <hip/hip_runtime.h>
#include <stdint.h>

#define GLOBAL_AS __attribute__((address_space(1)))
#define LDS_AS __attribute__((address_space(3)))

typedef int v4i  __attribute__((ext_vector_type(4)));
typedef int v16i __attribute__((ext_vector_type(16)));

static constexpr int M = 8192;
static constexpr int N = 4096;
static constexpr int K = 4096;
static constexpr float F_EPS = 1e-5f;

// ---------------- scalar init ----------------
__global__ void init_kernel(unsigned* gmax, double* gsum) {
    if (threadIdx.x == 0) { *gmax = 0u; *gsum = 0.0; }
}

// ---------------- absmax over x ----------------
__global__ void absmax_kernel(const float4* __restrict__ x, int n4, unsigned* __restrict__ gmax) {
    float m = 0.f;
    int stride = gridDim.x * blockDim.x;
    for (int i = blockIdx.x * blockDim.x + threadIdx.x; i < n4; i += stride) {
        float4 v = x[i];
        m = fmaxf(m, fmaxf(fmaxf(fabsf(v.x), fabsf(v.y)), fmaxf(fabsf(v.z), fabsf(v.w))));
    }
#pragma unroll
    for (int off = 32; off > 0; off >>= 1) m = fmaxf(m, __shfl_down(m, off, 64));
    __shared__ float red[4];
    if ((threadIdx.x & 63) == 0) red[threadIdx.x >> 6] = m;
    __syncthreads();
    if (threadIdx.x == 0) {
        m = fmaxf(fmaxf(red[0], red[1]), fmaxf(red[2], red[3]));
        atomicMax(gmax, __float_as_uint(m));  // all values >= 0: uint order == float order
    }
}

// ---------------- sum |W| (f64 accumulation) ----------------
__global__ void wsum_kernel(const float4* __restrict__ w, int n4, double* __restrict__ gsum) {
    double s = 0.0;
    int stride = gridDim.x * blockDim.x;
    for (int i = blockIdx.x * blockDim.x + threadIdx.x; i < n4; i += stride) {
        float4 v = w[i];
        s += (double)fabsf(v.x);
        s += (double)fabsf(v.y);
        s += (double)fabsf(v.z);
        s += (double)fabsf(v.w);
    }
#pragma unroll
    for (int off = 32; off > 0; off >>= 1) s += __shfl_down(s, off, 64);
    __shared__ double red[4];
    if ((threadIdx.x & 63) == 0) red[threadIdx.x >> 6] = s;
    __syncthreads();
    if (threadIdx.x == 0) {
        s = red[0] + red[1] + red[2] + red[3];
        atomicAdd(gsum, s);
    }
}

// ---------------- quantize x -> int8 ----------------
__global__ void quantx_kernel(const float4* __restrict__ x, int* __restrict__ xq, int n4,
                              const unsigned* __restrict__ gmax) {
    float gamma = fmaxf(__uint_as_float(*gmax), F_EPS);
    float s = 128.f / gamma;  // matches reference: q/gamma first, then multiply
    int stride = gridDim.x * blockDim.x;
    for (int i = blockIdx.x * blockDim.x + threadIdx.x; i < n4; i += stride) {
        float4 v = x[i];
        int q0 = min(127, max(-128, (int)rintf(v.x * s)));
        int q1 = min(127, max(-128, (int)rintf(v.y * s)));
        int q2 = min(127, max(-128, (int)rintf(v.z * s)));
        int q3 = min(127, max(-128, (int)rintf(v.w * s)));
        xq[i] = (q0 & 255) | ((q1 & 255) << 8) | ((q2 & 255) << 16) | (q3 << 24);
    }
}

// ---------------- quantize W -> ternary int8 ----------------
__global__ void quantw_kernel(const float4* __restrict__ w, int* __restrict__ wq, int n4,
                              const double* __restrict__ gsum) {
    float wscale = (float)fmax(*gsum * (1.0 / ((double)N * (double)K)), (double)F_EPS);
    int stride = gridDim.x * blockDim.x;
    for (int i = blockIdx.x * blockDim.x + threadIdx.x; i < n4; i += stride) {
        float4 v = w[i];
        // true f32 division to bit-match np's weight / w_scale
        int q0 = min(1, max(-1, (int)rintf(v.x / wscale)));
        int q1 = min(1, max(-1, (int)rintf(v.y / wscale)));
        int q2 = min(1, max(-1, (int)rintf(v.z / wscale)));
        int q3 = min(1, max(-1, (int)rintf(v.w / wscale)));
        wq[i] = (q0 & 255) | ((q1 & 255) << 8) | ((q2 & 255) << 16) | (q3 << 24);
    }
}

// ---------------- int8 GEMM: out[m][n] = sum_k xq[m][k]*wq[n][k], dequant + bias ----------------
// 128x128 block tile, BK=128, 256 threads (4 waves, each wave 64x64 via 2x2 of 32x32x32 i8 MFMA)
__global__ __launch_bounds__(256) void gemm_kernel(
    const int8_t* __restrict__ xq, const int8_t* __restrict__ wq,
    const float* __restrict__ bias, const unsigned* __restrict__ gmax,
    const double* __restrict__ gsum, float* __restrict__ out) {

    __shared__ __align__(16) int8_t As[128 * 128];
    __shared__ __align__(16) int8_t Bs[128 * 128];

    const int t = threadIdx.x;
    const int lane = t & 63;
    const int wv = t >> 6;
    const int half = lane >> 5;
    const int lr = lane & 31;
    const int wrow0 = (wv >> 1) * 64;
    const int wcol0 = (wv & 1) * 64;
    const int m0 = blockIdx.x * 128;
    const int n0 = blockIdx.y * 128;

    // dequant scale
    const float gamma = fmaxf(__uint_as_float(*gmax), F_EPS);
    const float wscale = (float)fmax(*gsum * (1.0 / ((double)N * (double)K)), (double)F_EPS);
    const float scale = gamma * wscale * (1.f / 128.f);

    // staging addresses: 4 issues x 16B per thread for each of A,B.
    // LDS row r (128B) holds global 16B-block c at slot (c ^ (r&7)) -> kills bank alignment.
    const GLOBAL_AS int8_t* aBase[4];
    const GLOBAL_AS int8_t* bBase[4];
    int ldsOff[4];
#pragma unroll
    for (int i = 0; i < 4; ++i) {
        int idx = i * 256 + t;      // 0..1023 16B-block index
        int r = idx >> 3;           // row 0..127
        int c = idx & 7;            // lds 16B slot
        int cg = c ^ (r & 7);       // global 16B column block
        aBase[i] = (const GLOBAL_AS int8_t*)(xq + (size_t)(m0 + r) * K + cg * 16);
        bBase[i] = (const GLOBAL_AS int8_t*)(wq + (size_t)(n0 + r) * K + cg * 16);
        ldsOff[i] = idx * 16;
    }

    v16i acc[2][2];
#pragma unroll
    for (int mt = 0; mt < 2; ++mt)
#pragma unroll
        for (int nt = 0; nt < 2; ++nt)
#pragma unroll
            for (int e = 0; e < 16; ++e) acc[mt][nt][e] = 0;

    const int aRow[2] = {wrow0 + lr, wrow0 + 32 + lr};
    const int bRow[2] = {wcol0 + lr, wcol0 + 32 + lr};

    for (int kt = 0; kt < K; kt += 128) {
#pragma unroll
        for (int i = 0; i < 4; ++i) {
            __builtin_amdgcn_global_load_lds((const GLOBAL_AS void*)(aBase[i] + kt),
                                             (LDS_AS void*)&As[ldsOff[i]], 16, 0, 0);
            __builtin_amdgcn_global_load_lds((const GLOBAL_AS void*)(bBase[i] + kt),
                                             (LDS_AS void*)&Bs[ldsOff[i]], 16, 0, 0);
        }
        __builtin_amdgcn_s_waitcnt(0);
        __syncthreads();

#pragma unroll
        for (int ks = 0; ks < 4; ++ks) {
            v4i a[2], b[2];
#pragma unroll
            for (int mt = 0; mt < 2; ++mt) {
                int r = aRow[mt];
                int cblk = (ks * 2 + half) ^ (r & 7);
                a[mt] = *(const v4i*)&As[r * 128 + cblk * 16];
            }
#pragma unroll
            for (int nt = 0; nt < 2; ++nt) {
                int r = bRow[nt];
                int cblk = (ks * 2 + half) ^ (r & 7);
                b[nt] = *(const v4i*)&Bs[r * 128 + cblk * 16];
            }
#pragma unroll
            for (int mt = 0; mt < 2; ++mt)
#pragma unroll
                for (int nt = 0; nt < 2; ++nt)
                    acc[mt][nt] = __builtin_amdgcn_mfma_i32_32x32x32_i8(a[mt], b[nt], acc[mt][nt], 0, 0, 0);
        }
        __syncthreads();
    }

    // epilogue: C/D layout col=lane&31, row=(reg&3)+8*(reg>>2)+4*(lane>>5)
#pragma unroll
    for (int mt = 0; mt < 2; ++mt) {
#pragma unroll
        for (int nt = 0; nt < 2; ++nt) {
            int col = n0 + wcol0 + nt * 32 + lr;
            float bv = bias[col];
#pragma unroll
            for (int reg = 0; reg < 16; ++reg) {
                int row = m0 + wrow0 + mt * 32 + 4 * half + (reg & 3) + 8 * (reg >> 2);
                out[(size_t)row * N + col] = (float)acc[mt][nt][reg] * scale + bv;
            }
        }
    }
}

extern "C" void kernel_launch(void* const* d_in, const int* in_sizes, int n_in,
                              void* d_out, int out_size, void* d_ws, size_t ws_size,
                              hipStream_t stream) {
    const float* x = (const float*)d_in[0];     // [8192][4096]
    const float* w = (const float*)d_in[1];     // [4096][4096]
    const float* bias = (const float*)d_in[2];  // [4096]
    float* out = (float*)d_out;                 // [8192][4096]

    unsigned* gmax = (unsigned*)d_ws;
    double* gsum = (double*)((char*)d_ws + 8);
    int8_t* xq = (int8_t*)d_ws + 16;            // 32 MiB
    int8_t* wq = xq + (size_t)M * K;            // 16 MiB

    hipLaunchKernelGGL(init_kernel, dim3(1), dim3(64), 0, stream, gmax, gsum);
    hipLaunchKernelGGL(absmax_kernel, dim3(1024), dim3(256), 0, stream,
                       (const float4*)x, M * K / 4, gmax);
    hipLaunchKernelGGL(wsum_kernel, dim3(512), dim3(256), 0, stream,
                       (const float4*)w, N * K / 4, gsum);
    hipLaunchKernelGGL(quantx_kernel, dim3(2048), dim3(256), 0, stream,
                       (const float4*)x, (int*)xq, M * K / 4, gmax);
    hipLaunchKernelGGL(quantw_kernel, dim3(1024), dim3(256), 0, stream,
                       (const float4*)w, (int*)wq, N * K / 4, gsum);
    hipLaunchKernelGGL(gemm_kernel, dim3(M / 128, N / 128), dim3(256), 0, stream,
                       xq, wq, bias, gmax, gsum, out);
}